// Round 8
// baseline (360.530 us; speedup 1.0000x reference)
//
#include <hip/hip_runtime.h>

#define RR 8
#define TILE 32
#define EXT (TILE + 2 * RR)   // 48

typedef float f4 __attribute__((ext_vector_type(4)));

// Kernel 1: per low-res pixel A = cov/(var+eps), b = mean_y - A*mean_x via
// clamped 17x17 box sums (zero-pad OOB + analytic N). Separable with
// register sliding windows to minimize LDS instruction count.
// Output: interleaved (A,b) float2 so k_out reads pairs with one b64.
__global__ __launch_bounds__(256) void k_ab(
    const float* __restrict__ lrx, const float* __restrict__ lry,
    float2* __restrict__ ABout, int H, int W) {
  __shared__ float sx[EXT][EXT];
  __shared__ float sy[EXT][EXT];
  __shared__ float hx[EXT][TILE];
  __shared__ float hy[EXT][TILE];
  __shared__ float hxy[EXT][TILE];
  __shared__ float hxx[EXT][TILE];

  const int bc = blockIdx.z;
  const size_t plane = (size_t)bc * H * W;
  const float* __restrict__ px = lrx + plane;
  const float* __restrict__ py = lry + plane;
  const int tx0 = blockIdx.x * TILE;
  const int ty0 = blockIdx.y * TILE;
  const int tid = threadIdx.y * 32 + threadIdx.x;  // block = 32x8 = 256

  // Stage 48x48 region. Interior blocks (no clamping needed): float4 loads.
  const bool interior = (tx0 >= RR) && (ty0 >= RR) &&
                        (tx0 + TILE + RR <= W) && (ty0 + TILE + RR <= H);
  if (interior) {
    const size_t base = (size_t)(ty0 - RR) * W + (tx0 - RR);
    for (int i = tid; i < EXT * (EXT / 4); i += 256) {  // 48*12 = 576
      int r = i / (EXT / 4);
      int c4 = (i - r * (EXT / 4)) * 4;
      size_t o = base + (size_t)r * W + c4;
      *(float4*)&sx[r][c4] = *(const float4*)(px + o);
      *(float4*)&sy[r][c4] = *(const float4*)(py + o);
    }
  } else {
    for (int i = tid; i < EXT * EXT; i += 256) {
      int r = i / EXT, c = i % EXT;
      int gy = ty0 + r - RR, gx = tx0 + c - RR;
      float vx = 0.f, vy = 0.f;
      if (gy >= 0 && gy < H && gx >= 0 && gx < W) {
        size_t o = (size_t)gy * W + gx;
        vx = px[o];
        vy = py[o];
      }
      sx[r][c] = vx;
      sy[r][c] = vy;
    }
  }
  __syncthreads();

  // Horizontal 17-tap sums: 48 rows x 8 groups of 4 outputs = 384 work items.
  for (int q = tid; q < EXT * (TILE / 4); q += 256) {
    int r = q >> 3;
    int c0 = (q & 7) * 4;
    float xv[20], yv[20];
#pragma unroll
    for (int t = 0; t < 5; ++t) {
      float4 x4 = *(const float4*)&sx[r][c0 + 4 * t];
      float4 y4 = *(const float4*)&sy[r][c0 + 4 * t];
      xv[4 * t + 0] = x4.x; xv[4 * t + 1] = x4.y; xv[4 * t + 2] = x4.z; xv[4 * t + 3] = x4.w;
      yv[4 * t + 0] = y4.x; yv[4 * t + 1] = y4.y; yv[4 * t + 2] = y4.z; yv[4 * t + 3] = y4.w;
    }
    float pv[20], qv[20];
#pragma unroll
    for (int i = 0; i < 20; ++i) { pv[i] = xv[i] * yv[i]; qv[i] = xv[i] * xv[i]; }
    float ax = 0.f, ay = 0.f, axy = 0.f, axx = 0.f;
#pragma unroll
    for (int i = 0; i < 17; ++i) { ax += xv[i]; ay += yv[i]; axy += pv[i]; axx += qv[i]; }
    float4 ox, oy, oxy, oxx;
    ox.x = ax; oy.x = ay; oxy.x = axy; oxx.x = axx;
#pragma unroll
    for (int j = 1; j < 4; ++j) {
      ax += xv[j + 16] - xv[j - 1];
      ay += yv[j + 16] - yv[j - 1];
      axy += pv[j + 16] - pv[j - 1];
      axx += qv[j + 16] - qv[j - 1];
      (&ox.x)[j] = ax; (&oy.x)[j] = ay; (&oxy.x)[j] = axy; (&oxx.x)[j] = axx;
    }
    *(float4*)&hx[r][c0] = ox;
    *(float4*)&hy[r][c0] = oy;
    *(float4*)&hxy[r][c0] = oxy;
    *(float4*)&hxx[r][c0] = oxx;
  }
  __syncthreads();

  // Vertical 17-tap: thread (tx, ty) computes rows ty*4..ty*4+3 at col tx.
  const int c = threadIdx.x;
  const int r0 = threadIdx.y * 4;
  float vx[20], vy[20], vxy[20], vxx[20];
#pragma unroll
  for (int i = 0; i < 20; ++i) {
    vx[i] = hx[r0 + i][c];
    vy[i] = hy[r0 + i][c];
    vxy[i] = hxy[r0 + i][c];
    vxx[i] = hxx[r0 + i][c];
  }
  float sX = 0.f, sY = 0.f, sXY = 0.f, sXX = 0.f;
#pragma unroll
  for (int i = 0; i < 17; ++i) { sX += vx[i]; sY += vy[i]; sXY += vxy[i]; sXX += vxx[i]; }

  const int gx = tx0 + c;
  const int nx = min(gx + RR, W - 1) - max(gx - RR, 0) + 1;
#pragma unroll
  for (int j = 0; j < 4; ++j) {
    if (j > 0) {
      sX += vx[j + 16] - vx[j - 1];
      sY += vy[j + 16] - vy[j - 1];
      sXY += vxy[j + 16] - vxy[j - 1];
      sXX += vxx[j + 16] - vxx[j - 1];
    }
    const int gy = ty0 + r0 + j;
    const int ny = min(gy + RR, H - 1) - max(gy - RR, 0) + 1;
    float inv = 1.f / (float)(nx * ny);
    float mx = sX * inv;
    float my = sY * inv;
    float cov = sXY * inv - mx * my;
    float var = sXX * inv - mx * mx;
    float a = cov / (var + 1e-8f);
    float bv = my - a * mx;
    size_t o = plane + (size_t)gy * W + gx;
    ABout[o] = make_float2(a, bv);
  }
}

// Kernel 2: bilinear align-corners upsample of (A,b) fused with out = A*hr+b.
// PERSISTENT GRID-STRIDE form of R6's barrier-free kernel. 1024 blocks
// (4/CU, all resident) x 12 tiles each, 2-stage software pipeline: tile
// k+1's 9 AB window loads + 4 nt hr loads are issued into a second register
// window while tile k computes and stores -- the memory pipe never drains
// (one-shot blocks paid full load latency once per block with nothing to
// overlap; all 5 prior one-shot variants tied at ~100us vs ~68us floor).
// Tile ids ordered (bc, yg, xb) so concurrent blocks sweep one bc plane at
// a time (4 MB AB plane stays L2-resident). Per-tile math is identical to
// R6: 3x3 register window (3*scx<1, 3*scy<1), cndmask row/col selects,
// y-lerp once then x-lerp, nt load on hr / nt store on out.
#define ROWS 4
#define KO_BLOCKS 1024
#define KO_ITERS 12   // 12288 tiles total = 2 xb * 512 yg * 12 bc

struct KoWin {
  float2 q[3][3];
  f4 h[ROWS];
  size_t hrBase;
  int xg, v, yb;
};

__device__ __forceinline__ void ko_load(
    int id, int tid, const float2* __restrict__ AB,
    const float* __restrict__ hr, int hl, int wl, int Hh, int Wh,
    float scy, float scx, KoWin& w) {
  const int xbi = id & 1;
  const int yg = (id >> 1) & 511;
  const int bc = id >> 10;
  const int yb = yg * ROWS;
  const int xg = xbi * 1024 + tid * 4;
  int v = (int)((float)yb * scy);
  if (v > hl - 1) v = hl - 1;
  w.yb = yb;
  w.xg = xg;
  w.v = v;

  const int x00 = (int)((float)xg * scx);
  const int xc1 = (x00 + 1 > wl - 1) ? wl - 1 : x00 + 1;
  const int xc2 = (x00 + 2 > wl - 1) ? wl - 1 : x00 + 2;
  const size_t lrBase = (size_t)bc * hl * wl;
#pragma unroll
  for (int rr = 0; rr < 3; ++rr) {
    int yr = v + rr;
    if (yr > hl - 1) yr = hl - 1;
    const float2* __restrict__ Rp = AB + lrBase + (size_t)yr * wl;
    w.q[rr][0] = Rp[x00];
    w.q[rr][1] = Rp[xc1];
    w.q[rr][2] = Rp[xc2];
  }

  w.hrBase = ((size_t)bc * Hh + yb) * Wh + xg;
#pragma unroll
  for (int r = 0; r < ROWS; ++r)
    w.h[r] = __builtin_nontemporal_load((const f4*)(hr + w.hrBase + (size_t)r * Wh));
}

__device__ __forceinline__ void ko_compute(
    const KoWin& w, float* __restrict__ out, int hl, int Wh,
    float scy, float scx) {
  // Per-pixel x params (recomputed from xg: cheaper than carrying 8 regs).
  float wxv[4];
  int dsel[4];
  const float fx0 = (float)w.xg * scx;
  const int x00 = (int)fx0;
  wxv[0] = fx0 - (float)x00;
  dsel[0] = 0;
#pragma unroll
  for (int j = 1; j < 4; ++j) {
    float fx = (float)(w.xg + j) * scx;
    int x0 = (int)fx;
    wxv[j] = fx - (float)x0;
    dsel[j] = x0 - x00;  // 0 or 1
  }

#pragma unroll
  for (int r = 0; r < ROWS; ++r) {
    float fy = (float)(w.yb + r) * scy;
    int y0 = (int)fy;
    if (y0 > hl - 1) y0 = hl - 1;
    int y1 = y0 + 1;
    if (y1 > hl - 1) y1 = hl - 1;
    const float wy = fy - (float)y0;
    const int i0 = y0 - w.v;  // 0 or 1
    const int i1 = y1 - w.v;  // 0, 1, or 2
    float2 p00 = i0 ? w.q[1][0] : w.q[0][0];
    float2 p01 = i0 ? w.q[1][1] : w.q[0][1];
    float2 p02 = i0 ? w.q[1][2] : w.q[0][2];
    float2 p10 = (i1 == 0) ? w.q[0][0] : ((i1 == 1) ? w.q[1][0] : w.q[2][0]);
    float2 p11 = (i1 == 0) ? w.q[0][1] : ((i1 == 1) ? w.q[1][1] : w.q[2][1]);
    float2 p12 = (i1 == 0) ? w.q[0][2] : ((i1 == 1) ? w.q[1][2] : w.q[2][2]);
    float w0a = p00.x + (p10.x - p00.x) * wy;
    float w0b = p00.y + (p10.y - p00.y) * wy;
    float w1a = p01.x + (p11.x - p01.x) * wy;
    float w1b = p01.y + (p11.y - p01.y) * wy;
    float w2a = p02.x + (p12.x - p02.x) * wy;
    float w2b = p02.y + (p12.y - p02.y) * wy;
    f4 res;
#pragma unroll
    for (int j = 0; j < 4; ++j) {
      float loa = dsel[j] ? w1a : w0a;
      float lob = dsel[j] ? w1b : w0b;
      float hia = dsel[j] ? w2a : w1a;
      float hib = dsel[j] ? w2b : w1b;
      float wxj = wxv[j];
      float a = loa + (hia - loa) * wxj;
      float b = lob + (hib - lob) * wxj;
      res[j] = a * w.h[r][j] + b;
    }
    __builtin_nontemporal_store(res, (f4*)(out + w.hrBase + (size_t)r * Wh));
  }
}

__global__ __launch_bounds__(256) void k_out(
    const float2* __restrict__ AB, const float* __restrict__ hr,
    float* __restrict__ out, int hl, int wl, int Hh, int Wh) {
  const int tid = threadIdx.x;
  const float scy = (float)(hl - 1) / (float)(Hh - 1);
  const float scx = (float)(wl - 1) / (float)(Wh - 1);

  KoWin w0, w1;  // statically named double buffer (no runtime reg indexing)
  int id = blockIdx.x;
  ko_load(id, tid, AB, hr, hl, wl, Hh, Wh, scy, scx, w0);
#pragma unroll 1
  for (int k = 0; k < KO_ITERS; k += 2) {
    ko_load(id + KO_BLOCKS, tid, AB, hr, hl, wl, Hh, Wh, scy, scx, w1);
    ko_compute(w0, out, hl, Wh, scy, scx);
    if (k + 2 < KO_ITERS)
      ko_load(id + 2 * KO_BLOCKS, tid, AB, hr, hl, wl, Hh, Wh, scy, scx, w0);
    ko_compute(w1, out, hl, Wh, scy, scx);
    id += 2 * KO_BLOCKS;
  }
}

extern "C" void kernel_launch(void* const* d_in, const int* in_sizes, int n_in,
                              void* d_out, int out_size, void* d_ws, size_t ws_size,
                              hipStream_t stream) {
  const float* lrx = (const float*)d_in[0];
  const float* lry = (const float*)d_in[1];
  const float* hrx = (const float*)d_in[2];
  float* out = (float*)d_out;

  const int BC = 12;  // 4 batch * 3 channels
  const int hl = 512, wl = 512;
  const int Hh = 2048, Wh = 2048;

  float2* AB = (float2*)d_ws;  // interleaved (A,b), 25 MB

  dim3 g1(wl / TILE, hl / TILE, BC);
  dim3 b1(32, 8);
  k_ab<<<g1, b1, 0, stream>>>(lrx, lry, AB, hl, wl);

  dim3 g2(KO_BLOCKS);
  dim3 b2(256);
  k_out<<<g2, b2, 0, stream>>>(AB, hrx, out, hl, wl, Hh, Wh);
}